// Round 4
// baseline (663.527 us; speedup 1.0000x reference)
//
#include <hip/hip_runtime.h>

#define LATENT 64
#define BUCKET_SHIFT 5
#define BUCKET_ROWS 32
#define COL_MASK 0xFFFFF   // 20 bits; requires N <= 2^20

// ---------------------------------------------------------------------------
// CSR build: histogram + hierarchical scan
// ---------------------------------------------------------------------------

__global__ void histogram_kernel(const int* __restrict__ rows, int* __restrict__ cnt, int E) {
    int e = blockIdx.x * blockDim.x + threadIdx.x;
    if (e < E) atomicAdd(&cnt[rows[e]], 1);
}

__global__ void block_sum_kernel(const int* __restrict__ cnt, int* __restrict__ bsum, int N) {
    __shared__ int s[256];
    int t = threadIdx.x;
    int i = blockIdx.x * 256 + t;
    s[t] = (i < N) ? cnt[i] : 0;
    __syncthreads();
    for (int o = 128; o > 0; o >>= 1) {
        if (t < o) s[t] += s[t + o];
        __syncthreads();
    }
    if (t == 0) bsum[blockIdx.x] = s[0];
}

__global__ void scan_partials_kernel(int* __restrict__ bsum, int nblk) {
    __shared__ int s[512];
    int t = threadIdx.x;
    int v = (t < nblk) ? bsum[t] : 0;
    s[t] = v;
    __syncthreads();
    for (int o = 1; o < 512; o <<= 1) {
        int u = (t >= o) ? s[t - o] : 0;
        __syncthreads();
        s[t] += u;
        __syncthreads();
    }
    if (t < nblk) bsum[t] = s[t] - v;   // exclusive
}

__global__ void chunk_scan_kernel(const int* __restrict__ cnt, const int* __restrict__ bsum,
                                  int* __restrict__ off, int N) {
    __shared__ int s[256];
    int t = threadIdx.x;
    int i = blockIdx.x * 256 + t;
    int v = (i < N) ? cnt[i] : 0;
    s[t] = v;
    __syncthreads();
    for (int o = 1; o < 256; o <<= 1) {
        int u = (t >= o) ? s[t - o] : 0;
        __syncthreads();
        s[t] += u;
        __syncthreads();
    }
    if (i < N) off[i] = s[t] - v + bsum[blockIdx.x];
}

// boff[b] = CSR offset of first row of bucket b; bcur = running cursor for pass 1
__global__ void bucket_init_kernel(const int* __restrict__ off, int* __restrict__ boff,
                                   int* __restrict__ bcur, int nbuckets, int E) {
    int b = blockIdx.x * blockDim.x + threadIdx.x;
    if (b <= nbuckets) {
        int v = (b < nbuckets) ? off[b << BUCKET_SHIFT] : E;
        boff[b] = v;
        if (b < nbuckets) bcur[b] = v;
    }
}

// ---------------------------------------------------------------------------
// Two-pass bucketed sort
// ---------------------------------------------------------------------------

// Pass 1: scatter edges into their bucket's contiguous region (only ~3125
// active cursors -> active write lines ~200KB, L2-resident -> no write amp).
// Payload 8B: {col | rowlocal<<20, val_bits}
__global__ void bucket_scatter_kernel(const int* __restrict__ rows, const int* __restrict__ cols,
                                      const float* __restrict__ vals, int* __restrict__ bcur,
                                      int2* __restrict__ tmp, int E) {
    int e = blockIdx.x * blockDim.x + threadIdx.x;
    if (e < E) {
        int r = rows[e];
        int p = atomicAdd(&bcur[r >> BUCKET_SHIFT], 1);
        tmp[p] = make_int2(cols[e] | ((r & (BUCKET_ROWS - 1)) << 20), __float_as_int(vals[e]));
    }
}

// Pass 2: one block per bucket. Sequential read of the bucket slice, LDS
// cursors per local row, final store lands in the bucket's ~8KB CSR window.
__global__ void bucket_sort_kernel(const int2* __restrict__ tmp, const int* __restrict__ boff,
                                   const int* __restrict__ off, int2* __restrict__ spair) {
    __shared__ int cur[BUCKET_ROWS];
    int b = blockIdx.x;
    int t = threadIdx.x;
    if (t < BUCKET_ROWS) cur[t] = 0;
    __syncthreads();
    int beg = boff[b], end = boff[b + 1];
    int base_row = b << BUCKET_SHIFT;
    for (int e = beg + t; e < end; e += blockDim.x) {
        int2 w = tmp[e];
        int rl = (w.x >> 20) & (BUCKET_ROWS - 1);
        int p = atomicAdd(&cur[rl], 1);
        spair[off[base_row + rl] + p] = make_int2(w.x & COL_MASK, w.y);
    }
}

// ---------------------------------------------------------------------------
// Gather SpMM: one 64-lane wave per output row; lane = feature index.
// ---------------------------------------------------------------------------

__global__ void spmm_gather_kernel(const int* __restrict__ off, const int* __restrict__ cnt,
                                   const int2* __restrict__ spair,
                                   const float* __restrict__ x, float* __restrict__ y, int N) {
    int wid = blockIdx.x * (blockDim.x >> 6) + (threadIdx.x >> 6);
    int lane = threadIdx.x & 63;
    if (wid >= N) return;
    int e = off[wid];
    int end = e + cnt[wid];
    float acc = 0.f;
    for (; e + 8 <= end; e += 8) {
        int2 p0 = spair[e], p1 = spair[e + 1], p2 = spair[e + 2], p3 = spair[e + 3];
        int2 p4 = spair[e + 4], p5 = spair[e + 5], p6 = spair[e + 6], p7 = spair[e + 7];
        acc += __int_as_float(p0.y) * x[(size_t)p0.x * LATENT + lane];
        acc += __int_as_float(p1.y) * x[(size_t)p1.x * LATENT + lane];
        acc += __int_as_float(p2.y) * x[(size_t)p2.x * LATENT + lane];
        acc += __int_as_float(p3.y) * x[(size_t)p3.x * LATENT + lane];
        acc += __int_as_float(p4.y) * x[(size_t)p4.x * LATENT + lane];
        acc += __int_as_float(p5.y) * x[(size_t)p5.x * LATENT + lane];
        acc += __int_as_float(p6.y) * x[(size_t)p6.x * LATENT + lane];
        acc += __int_as_float(p7.y) * x[(size_t)p7.x * LATENT + lane];
    }
    for (; e < end; ++e) {
        int2 p = spair[e];
        acc += __int_as_float(p.y) * x[(size_t)p.x * LATENT + lane];
    }
    y[(size_t)wid * LATENT + lane] = acc;
}

__global__ void spmm_gather_fused_kernel(const int* __restrict__ off, const int* __restrict__ cnt,
                                         const int2* __restrict__ spair,
                                         const float* __restrict__ ax1,
                                         const float* __restrict__ alpha,
                                         const float* __restrict__ x,
                                         float* __restrict__ out, int N) {
    int wid = blockIdx.x * (blockDim.x >> 6) + (threadIdx.x >> 6);
    int lane = threadIdx.x & 63;
    if (wid >= N) return;
    int e = off[wid];
    int end = e + cnt[wid];
    float acc = 0.f;
    for (; e + 8 <= end; e += 8) {
        int2 p0 = spair[e], p1 = spair[e + 1], p2 = spair[e + 2], p3 = spair[e + 3];
        int2 p4 = spair[e + 4], p5 = spair[e + 5], p6 = spair[e + 6], p7 = spair[e + 7];
        acc += __int_as_float(p0.y) * ax1[(size_t)p0.x * LATENT + lane];
        acc += __int_as_float(p1.y) * ax1[(size_t)p1.x * LATENT + lane];
        acc += __int_as_float(p2.y) * ax1[(size_t)p2.x * LATENT + lane];
        acc += __int_as_float(p3.y) * ax1[(size_t)p3.x * LATENT + lane];
        acc += __int_as_float(p4.y) * ax1[(size_t)p4.x * LATENT + lane];
        acc += __int_as_float(p5.y) * ax1[(size_t)p5.x * LATENT + lane];
        acc += __int_as_float(p6.y) * ax1[(size_t)p6.x * LATENT + lane];
        acc += __int_as_float(p7.y) * ax1[(size_t)p7.x * LATENT + lane];
    }
    for (; e < end; ++e) {
        int2 p = spair[e];
        acc += __int_as_float(p.y) * ax1[(size_t)p.x * LATENT + lane];
    }
    float a = 1.0f / (1.0f + __expf(-alpha[wid]));
    out[(size_t)wid * LATENT + lane] = a * acc - x[(size_t)wid * LATENT + lane];
}

// ---------------------------------------------------------------------------
// Fallbacks
// ---------------------------------------------------------------------------

// Round-2 style direct scatter (used if ws too small for the bucketed path)
__global__ void scatter_kernel(const int* __restrict__ rows, const int* __restrict__ cols,
                               const float* __restrict__ vals, int* __restrict__ cursor,
                               int2* __restrict__ spair, int E) {
    int e = blockIdx.x * blockDim.x + threadIdx.x;
    if (e < E) {
        int r = rows[e];
        int p = atomicAdd(&cursor[r], 1);
        spair[p] = make_int2(cols[e], __float_as_int(vals[e]));
    }
}

__global__ void init_cursor_kernel(const int* __restrict__ off, int* __restrict__ cur, int N) {
    int i = blockIdx.x * blockDim.x + threadIdx.x;
    if (i < N) cur[i] = off[i];
}

__global__ void spmm_atomic_kernel(const int* __restrict__ rows, const int* __restrict__ cols,
                                   const float* __restrict__ vals, const float* __restrict__ x,
                                   float* __restrict__ y, int E) {
    long long tid = (long long)blockIdx.x * blockDim.x + threadIdx.x;
    long long total = (long long)E * 16;
    long long stride = (long long)gridDim.x * blockDim.x;
    for (; tid < total; tid += stride) {
        int e = (int)(tid >> 4);
        int q = (int)(tid & 15);
        int r = rows[e];
        int c = cols[e];
        float v = vals[e];
        float4 xv = reinterpret_cast<const float4*>(x)[(size_t)c * 16 + q];
        float* yp = y + (size_t)r * LATENT + q * 4;
        atomicAdd(yp + 0, v * xv.x);
        atomicAdd(yp + 1, v * xv.y);
        atomicAdd(yp + 2, v * xv.z);
        atomicAdd(yp + 3, v * xv.w);
    }
}

__global__ void finalize_kernel(const float* __restrict__ alpha, const float* __restrict__ x,
                                float* __restrict__ out, int N) {
    long long tid = (long long)blockIdx.x * blockDim.x + threadIdx.x;
    long long total = (long long)N * 16;
    long long stride = (long long)gridDim.x * blockDim.x;
    for (; tid < total; tid += stride) {
        int i = (int)(tid >> 4);
        float a = 1.0f / (1.0f + __expf(-alpha[i]));
        float4 o = reinterpret_cast<float4*>(out)[tid];
        float4 xv = reinterpret_cast<const float4*>(x)[tid];
        o.x = a * o.x - xv.x;
        o.y = a * o.y - xv.y;
        o.z = a * o.z - xv.z;
        o.w = a * o.w - xv.w;
        reinterpret_cast<float4*>(out)[tid] = o;
    }
}

// ---------------------------------------------------------------------------

extern "C" void kernel_launch(void* const* d_in, const int* in_sizes, int n_in,
                              void* d_out, int out_size, void* d_ws, size_t ws_size,
                              hipStream_t stream) {
    // setup_inputs order: t, x, alpha_train, edge_rows, edge_cols, edge_vals
    const float* x     = (const float*)d_in[1];
    const float* alpha = (const float*)d_in[2];
    const int*   rows  = (const int*)d_in[3];
    const int*   cols  = (const int*)d_in[4];
    const float* vals  = (const float*)d_in[5];

    const int N = in_sizes[2];   // 100000
    const int E = in_sizes[3];   // 3200000
    float* out = (float*)d_out;

    const int block = 256;
    const int nblk_N = (N + 255) / 256;
    const int nbuckets = (N + BUCKET_ROWS - 1) >> BUCKET_SHIFT;
    const int grid_E = (E + block - 1) / block;

    auto align256 = [](size_t v) { return (v + 255) & ~(size_t)255; };

    // Workspace layout for the bucketed path. tmp (pass-1 staging, E*8B) and
    // ax1 (N*256B) have disjoint lifetimes -> share the same region.
    size_t regionA  = (size_t)E * sizeof(int2);
    size_t regionA2 = (size_t)N * LATENT * sizeof(float);
    if (regionA2 > regionA) regionA = regionA2;
    size_t o_tmp   = 0;                                    // tmp | ax1
    size_t o_spair = align256(o_tmp + regionA);
    size_t o_cnt   = align256(o_spair + (size_t)E * sizeof(int2));
    size_t o_off   = align256(o_cnt + (size_t)N * sizeof(int));
    size_t o_bsum  = align256(o_off + (size_t)N * sizeof(int));
    size_t o_boff  = align256(o_bsum + 512 * sizeof(int));
    size_t o_bcur  = align256(o_boff + (size_t)(nbuckets + 1) * sizeof(int));
    size_t needed  = o_bcur + (size_t)nbuckets * sizeof(int);

    if (ws_size >= needed && nblk_N <= 512 && N <= (1 << 20)) {
        char* ws = (char*)d_ws;
        int2*  tmp   = (int2*)(ws + o_tmp);
        float* ax1   = (float*)(ws + o_tmp);               // aliases tmp
        int2*  spair = (int2*)(ws + o_spair);
        int*   cnt   = (int*)(ws + o_cnt);
        int*   off   = (int*)(ws + o_off);
        int*   bsum  = (int*)(ws + o_bsum);
        int*   boff  = (int*)(ws + o_boff);
        int*   bcur  = (int*)(ws + o_bcur);

        // CSR offsets
        hipMemsetAsync(cnt, 0, (size_t)N * sizeof(int), stream);
        histogram_kernel<<<grid_E, block, 0, stream>>>(rows, cnt, E);
        block_sum_kernel<<<nblk_N, 256, 0, stream>>>(cnt, bsum, N);
        scan_partials_kernel<<<1, 512, 0, stream>>>(bsum, nblk_N);
        chunk_scan_kernel<<<nblk_N, 256, 0, stream>>>(cnt, bsum, off, N);
        bucket_init_kernel<<<(nbuckets + 256) / 256, 256, 0, stream>>>(off, boff, bcur,
                                                                       nbuckets, E);

        // Two-pass bucketed sort into CSR order
        bucket_scatter_kernel<<<grid_E, block, 0, stream>>>(rows, cols, vals, bcur, tmp, E);
        bucket_sort_kernel<<<nbuckets, block, 0, stream>>>(tmp, boff, off, spair);

        // Two gather hops (one wave per row, 4 waves per block); tmp is dead
        // now, its region becomes ax1.
        int rows_per_block = block / 64;
        int grid_rows = (N + rows_per_block - 1) / rows_per_block;
        spmm_gather_kernel<<<grid_rows, block, 0, stream>>>(off, cnt, spair, x, ax1, N);
        spmm_gather_fused_kernel<<<grid_rows, block, 0, stream>>>(off, cnt, spair, ax1,
                                                                  alpha, x, out, N);
        return;
    }

    // Fallback A: round-2 layout (direct scatter), if it fits
    size_t f_ax1   = 0;
    size_t f_spair = align256(f_ax1 + (size_t)N * LATENT * sizeof(float));
    size_t f_cnt   = align256(f_spair + (size_t)E * sizeof(int2));
    size_t f_off   = align256(f_cnt + (size_t)N * sizeof(int));
    size_t f_cur   = align256(f_off + (size_t)N * sizeof(int));
    size_t f_bsum  = align256(f_cur + (size_t)N * sizeof(int));
    size_t f_need  = f_bsum + 512 * sizeof(int);

    if (ws_size >= f_need && nblk_N <= 512) {
        char* ws = (char*)d_ws;
        float* ax1   = (float*)(ws + f_ax1);
        int2*  spair = (int2*)(ws + f_spair);
        int*   cnt   = (int*)(ws + f_cnt);
        int*   off   = (int*)(ws + f_off);
        int*   cur   = (int*)(ws + f_cur);
        int*   bsum  = (int*)(ws + f_bsum);

        hipMemsetAsync(cnt, 0, (size_t)N * sizeof(int), stream);
        histogram_kernel<<<grid_E, block, 0, stream>>>(rows, cnt, E);
        block_sum_kernel<<<nblk_N, 256, 0, stream>>>(cnt, bsum, N);
        scan_partials_kernel<<<1, 512, 0, stream>>>(bsum, nblk_N);
        chunk_scan_kernel<<<nblk_N, 256, 0, stream>>>(cnt, bsum, off, N);
        init_cursor_kernel<<<nblk_N, 256, 0, stream>>>(off, cur, N);
        scatter_kernel<<<grid_E, block, 0, stream>>>(rows, cols, vals, cur, spair, E);

        int rows_per_block = block / 64;
        int grid_rows = (N + rows_per_block - 1) / rows_per_block;
        spmm_gather_kernel<<<grid_rows, block, 0, stream>>>(off, cnt, spair, x, ax1, N);
        spmm_gather_fused_kernel<<<grid_rows, block, 0, stream>>>(off, cnt, spair, ax1,
                                                                  alpha, x, out, N);
        return;
    }

    // Fallback B: atomic scatter path
    {
        float* ax1 = (float*)d_ws;
        const size_t feat_bytes = (size_t)N * LATENT * sizeof(float);
        hipMemsetAsync(ax1, 0, feat_bytes, stream);
        hipMemsetAsync(out, 0, feat_bytes, stream);
        long long work = (long long)E * 16;
        int grid_spmm = (int)((work + block - 1) / block);
        spmm_atomic_kernel<<<grid_spmm, block, 0, stream>>>(rows, cols, vals, x, ax1, E);
        spmm_atomic_kernel<<<grid_spmm, block, 0, stream>>>(rows, cols, vals, ax1, out, E);
        long long fwork = (long long)N * 16;
        int grid_fin = (int)((fwork + block - 1) / block);
        finalize_kernel<<<grid_fin, block, 0, stream>>>(alpha, x, out, N);
    }
}

// Round 5
// 545.862 us; speedup vs baseline: 1.2156x; 1.2156x over previous
//
#include <hip/hip_runtime.h>

#define LATENT 64
#define SUB_SHIFT 7
#define SUB_ROWS 128
#define COLBITS 17
#define COL_MASK ((1 << COLBITS) - 1)
#define HIST_BLOCKS 256
#define TILE 8192
#define NSUB_PAD 1024

// ---------------------------------------------------------------------------
// Kernel A: per-block sub-bucket histogram partials (no global atomics)
// ---------------------------------------------------------------------------
__global__ void subhist_kernel(const int* __restrict__ rows, int* __restrict__ part,
                               int E, int nsub) {
    __shared__ int h[NSUB_PAD];
    int t = threadIdx.x;
    for (int i = t; i < NSUB_PAD; i += blockDim.x) h[i] = 0;
    __syncthreads();
    for (int e = blockIdx.x * blockDim.x + t; e < E; e += gridDim.x * blockDim.x)
        atomicAdd(&h[rows[e] >> SUB_SHIFT], 1);
    __syncthreads();
    for (int i = t; i < nsub; i += blockDim.x) part[blockIdx.x * nsub + i] = h[i];
}

// ---------------------------------------------------------------------------
// Kernel B (1 block): reduce partials + exclusive scan -> csr0, tstart, stot, gcur
// tstart[s] = csr0[s] + 8*s  (8-payload gap => adjacent bins never share a line)
// ---------------------------------------------------------------------------
__global__ void subscan_kernel(const int* __restrict__ part, int* __restrict__ csr0,
                               int* __restrict__ tstart, int* __restrict__ stot,
                               int* __restrict__ gcur, int nsub, int nblk) {
    __shared__ int tot[NSUB_PAD];
    __shared__ int sc[256];
    int t = threadIdx.x;
    for (int i = t; i < NSUB_PAD; i += 256) tot[i] = 0;
    __syncthreads();
    for (int s = t; s < nsub; s += 256) {
        int acc = 0;
        for (int b = 0; b < nblk; ++b) acc += part[b * nsub + s];
        tot[s] = acc;
    }
    __syncthreads();
    int c0 = tot[4 * t], c1 = tot[4 * t + 1], c2 = tot[4 * t + 2], c3 = tot[4 * t + 3];
    int csum = c0 + c1 + c2 + c3;
    sc[t] = csum;
    __syncthreads();
    for (int o = 1; o < 256; o <<= 1) {
        int u = (t >= o) ? sc[t - o] : 0;
        __syncthreads();
        sc[t] += u;
        __syncthreads();
    }
    int pre = sc[t] - csum;   // exclusive chunk base
    int s0 = 4 * t;
    if (s0 < nsub)     { csr0[s0] = pre;     stot[s0] = c0;     int ts = pre + 8 * s0;           tstart[s0] = ts;     gcur[s0] = ts; }
    pre += c0;
    if (s0 + 1 < nsub) { csr0[s0 + 1] = pre; stot[s0 + 1] = c1; int ts = pre + 8 * (s0 + 1);     tstart[s0 + 1] = ts; gcur[s0 + 1] = ts; }
    pre += c1;
    if (s0 + 2 < nsub) { csr0[s0 + 2] = pre; stot[s0 + 2] = c2; int ts = pre + 8 * (s0 + 2);     tstart[s0 + 2] = ts; gcur[s0 + 2] = ts; }
    pre += c2;
    if (s0 + 3 < nsub) { csr0[s0 + 3] = pre; stot[s0 + 3] = c3; int ts = pre + 8 * (s0 + 3);     tstart[s0 + 3] = ts; gcur[s0 + 3] = ts; }
}

// ---------------------------------------------------------------------------
// Pass 1: tile-local LDS bucket sort, then append contiguous runs to bins.
// Each run is written by consecutive threads of ONE block -> single-CU lines.
// ---------------------------------------------------------------------------
__global__ void __launch_bounds__(256, 2) binscatter_kernel(
        const int* __restrict__ rows, const int* __restrict__ cols,
        const float* __restrict__ vals, int* __restrict__ gcur,
        int2* __restrict__ tmp, int E, int nsub) {
    __shared__ int hist[NSUB_PAD];    // histogram, then cursor
    __shared__ int base[NSUB_PAD];    // exclusive scan (sentinel semantics at nsub)
    __shared__ int gbase[NSUB_PAD];   // global run start - local base
    __shared__ int2 stage[TILE];
    __shared__ int sc[256];
    int t = threadIdx.x;
    int tb = blockIdx.x * TILE;
    int tilecnt = E - tb; if (tilecnt > TILE) tilecnt = TILE;

    for (int i = t; i < NSUB_PAD; i += 256) hist[i] = 0;
    __syncthreads();
    #pragma unroll
    for (int k = 0; k < TILE / 256; ++k) {
        int e = tb + k * 256 + t;
        if (e < E) atomicAdd(&hist[rows[e] >> SUB_SHIFT], 1);
    }
    __syncthreads();
    // exclusive scan hist -> base over NSUB_PAD (chunk of 4 per thread)
    int c0 = hist[4 * t], c1 = hist[4 * t + 1], c2 = hist[4 * t + 2], c3 = hist[4 * t + 3];
    int csum = c0 + c1 + c2 + c3;
    sc[t] = csum;
    __syncthreads();
    for (int o = 1; o < 256; o <<= 1) {
        int u = (t >= o) ? sc[t - o] : 0;
        __syncthreads();
        sc[t] += u;
        __syncthreads();
    }
    int ex = sc[t] - csum;
    base[4 * t] = ex;
    base[4 * t + 1] = ex + c0;
    base[4 * t + 2] = ex + c0 + c1;
    base[4 * t + 3] = ex + c0 + c1 + c2;
    __syncthreads();
    for (int i = t; i < NSUB_PAD; i += 256) hist[i] = 0;   // reset as cursors
    __syncthreads();
    // place payloads into stage, sorted by bucket
    #pragma unroll
    for (int k = 0; k < TILE / 256; ++k) {
        int e = tb + k * 256 + t;
        if (e < E) {
            int r = rows[e];
            int b = r >> SUB_SHIFT;
            int pos = base[b] + atomicAdd(&hist[b], 1);
            stage[pos] = make_int2(cols[e] | ((r & (SUB_ROWS - 1)) << COLBITS),
                                   __float_as_int(vals[e]));
        }
    }
    __syncthreads();
    // reserve global space (one atomic per non-empty bucket per tile)
    for (int i = t; i < nsub; i += 256) {
        int n = hist[i];
        int gb = 0;
        if (n > 0) gb = atomicAdd(&gcur[i], n);
        gbase[i] = gb - base[i];
    }
    __syncthreads();
    // copy out: consecutive p -> consecutive dst within each run (coalesced)
    for (int p = t; p < tilecnt; p += 256) {
        int lo = 0, hi = nsub;
        while (hi - lo > 1) { int mid = (lo + hi) >> 1; if (base[mid] <= p) lo = mid; else hi = mid; }
        tmp[gbase[lo] + p] = stage[p];
    }
}

// ---------------------------------------------------------------------------
// Pass 2: one block per sub-bucket -> per-row counts, off/cnt, sorted spair.
// All writes land in the block's private ~32KB CSR window (single XCD).
// ---------------------------------------------------------------------------
__global__ void subsort_kernel(const int2* __restrict__ tmp, const int* __restrict__ tstart,
                               const int* __restrict__ stot, const int* __restrict__ csr0,
                               int* __restrict__ off, int* __restrict__ cnt,
                               int2* __restrict__ spair, int N) {
    __shared__ int lcnt[SUB_ROWS], lpos[SUB_ROWS], lcur[SUB_ROWS];
    int s = blockIdx.x;
    int t = threadIdx.x;
    int beg = tstart[s], n = stot[s], c0 = csr0[s];
    if (t < SUB_ROWS) lcnt[t] = 0;
    __syncthreads();
    for (int i = t; i < n; i += blockDim.x)
        atomicAdd(&lcnt[(tmp[beg + i].x >> COLBITS) & (SUB_ROWS - 1)], 1);
    __syncthreads();
    if (t < SUB_ROWS) lpos[t] = lcnt[t];
    __syncthreads();
    for (int o = 1; o < SUB_ROWS; o <<= 1) {
        int u = (t < SUB_ROWS && t >= o) ? lpos[t - o] : 0;
        __syncthreads();
        if (t < SUB_ROWS) lpos[t] += u;
        __syncthreads();
    }
    if (t < SUB_ROWS) {
        int excl = lpos[t] - lcnt[t];
        lcur[t] = excl;
        int row = (s << SUB_SHIFT) + t;
        if (row < N) { off[row] = c0 + excl; cnt[row] = lcnt[t]; }
    }
    __syncthreads();
    for (int i = t; i < n; i += blockDim.x) {
        int2 w = tmp[beg + i];
        int rl = (w.x >> COLBITS) & (SUB_ROWS - 1);
        int p = atomicAdd(&lcur[rl], 1);
        spair[c0 + p] = make_int2(w.x & COL_MASK, w.y);
    }
}

// ---------------------------------------------------------------------------
// Gather SpMM: one 64-lane wave per output row; lane = feature index.
// ---------------------------------------------------------------------------
__global__ void spmm_gather_kernel(const int* __restrict__ off, const int* __restrict__ cnt,
                                   const int2* __restrict__ spair,
                                   const float* __restrict__ x, float* __restrict__ y, int N) {
    int wid = blockIdx.x * (blockDim.x >> 6) + (threadIdx.x >> 6);
    int lane = threadIdx.x & 63;
    if (wid >= N) return;
    int e = off[wid];
    int end = e + cnt[wid];
    float acc = 0.f;
    for (; e + 8 <= end; e += 8) {
        int2 p0 = spair[e], p1 = spair[e + 1], p2 = spair[e + 2], p3 = spair[e + 3];
        int2 p4 = spair[e + 4], p5 = spair[e + 5], p6 = spair[e + 6], p7 = spair[e + 7];
        acc += __int_as_float(p0.y) * x[(size_t)p0.x * LATENT + lane];
        acc += __int_as_float(p1.y) * x[(size_t)p1.x * LATENT + lane];
        acc += __int_as_float(p2.y) * x[(size_t)p2.x * LATENT + lane];
        acc += __int_as_float(p3.y) * x[(size_t)p3.x * LATENT + lane];
        acc += __int_as_float(p4.y) * x[(size_t)p4.x * LATENT + lane];
        acc += __int_as_float(p5.y) * x[(size_t)p5.x * LATENT + lane];
        acc += __int_as_float(p6.y) * x[(size_t)p6.x * LATENT + lane];
        acc += __int_as_float(p7.y) * x[(size_t)p7.x * LATENT + lane];
    }
    for (; e < end; ++e) {
        int2 p = spair[e];
        acc += __int_as_float(p.y) * x[(size_t)p.x * LATENT + lane];
    }
    y[(size_t)wid * LATENT + lane] = acc;
}

__global__ void spmm_gather_fused_kernel(const int* __restrict__ off, const int* __restrict__ cnt,
                                         const int2* __restrict__ spair,
                                         const float* __restrict__ ax1,
                                         const float* __restrict__ alpha,
                                         const float* __restrict__ x,
                                         float* __restrict__ out, int N) {
    int wid = blockIdx.x * (blockDim.x >> 6) + (threadIdx.x >> 6);
    int lane = threadIdx.x & 63;
    if (wid >= N) return;
    int e = off[wid];
    int end = e + cnt[wid];
    float acc = 0.f;
    for (; e + 8 <= end; e += 8) {
        int2 p0 = spair[e], p1 = spair[e + 1], p2 = spair[e + 2], p3 = spair[e + 3];
        int2 p4 = spair[e + 4], p5 = spair[e + 5], p6 = spair[e + 6], p7 = spair[e + 7];
        acc += __int_as_float(p0.y) * ax1[(size_t)p0.x * LATENT + lane];
        acc += __int_as_float(p1.y) * ax1[(size_t)p1.x * LATENT + lane];
        acc += __int_as_float(p2.y) * ax1[(size_t)p2.x * LATENT + lane];
        acc += __int_as_float(p3.y) * ax1[(size_t)p3.x * LATENT + lane];
        acc += __int_as_float(p4.y) * ax1[(size_t)p4.x * LATENT + lane];
        acc += __int_as_float(p5.y) * ax1[(size_t)p5.x * LATENT + lane];
        acc += __int_as_float(p6.y) * ax1[(size_t)p6.x * LATENT + lane];
        acc += __int_as_float(p7.y) * ax1[(size_t)p7.x * LATENT + lane];
    }
    for (; e < end; ++e) {
        int2 p = spair[e];
        acc += __int_as_float(p.y) * ax1[(size_t)p.x * LATENT + lane];
    }
    float a = 1.0f / (1.0f + __expf(-alpha[wid]));
    out[(size_t)wid * LATENT + lane] = a * acc - x[(size_t)wid * LATENT + lane];
}

// ---------------------------------------------------------------------------
// Fallback kernels (round-2 direct-scatter path + atomic path)
// ---------------------------------------------------------------------------
__global__ void histogram_kernel(const int* __restrict__ rows, int* __restrict__ cnt, int E) {
    int e = blockIdx.x * blockDim.x + threadIdx.x;
    if (e < E) atomicAdd(&cnt[rows[e]], 1);
}

__global__ void block_sum_kernel(const int* __restrict__ cnt, int* __restrict__ bsum, int N) {
    __shared__ int s[256];
    int t = threadIdx.x;
    int i = blockIdx.x * 256 + t;
    s[t] = (i < N) ? cnt[i] : 0;
    __syncthreads();
    for (int o = 128; o > 0; o >>= 1) {
        if (t < o) s[t] += s[t + o];
        __syncthreads();
    }
    if (t == 0) bsum[blockIdx.x] = s[0];
}

__global__ void scan_partials_kernel(int* __restrict__ bsum, int nblk) {
    __shared__ int s[512];
    int t = threadIdx.x;
    int v = (t < nblk) ? bsum[t] : 0;
    s[t] = v;
    __syncthreads();
    for (int o = 1; o < 512; o <<= 1) {
        int u = (t >= o) ? s[t - o] : 0;
        __syncthreads();
        s[t] += u;
        __syncthreads();
    }
    if (t < nblk) bsum[t] = s[t] - v;
}

__global__ void chunk_scan_kernel(const int* __restrict__ cnt, const int* __restrict__ bsum,
                                  int* __restrict__ off, int N) {
    __shared__ int s[256];
    int t = threadIdx.x;
    int i = blockIdx.x * 256 + t;
    int v = (i < N) ? cnt[i] : 0;
    s[t] = v;
    __syncthreads();
    for (int o = 1; o < 256; o <<= 1) {
        int u = (t >= o) ? s[t - o] : 0;
        __syncthreads();
        s[t] += u;
        __syncthreads();
    }
    if (i < N) off[i] = s[t] - v + bsum[blockIdx.x];
}

__global__ void init_cursor_kernel(const int* __restrict__ off, int* __restrict__ cur, int N) {
    int i = blockIdx.x * blockDim.x + threadIdx.x;
    if (i < N) cur[i] = off[i];
}

__global__ void scatter_kernel(const int* __restrict__ rows, const int* __restrict__ cols,
                               const float* __restrict__ vals, int* __restrict__ cursor,
                               int2* __restrict__ spair, int E) {
    int e = blockIdx.x * blockDim.x + threadIdx.x;
    if (e < E) {
        int r = rows[e];
        int p = atomicAdd(&cursor[r], 1);
        spair[p] = make_int2(cols[e], __float_as_int(vals[e]));
    }
}

__global__ void spmm_atomic_kernel(const int* __restrict__ rows, const int* __restrict__ cols,
                                   const float* __restrict__ vals, const float* __restrict__ x,
                                   float* __restrict__ y, int E) {
    long long tid = (long long)blockIdx.x * blockDim.x + threadIdx.x;
    long long total = (long long)E * 16;
    long long stride = (long long)gridDim.x * blockDim.x;
    for (; tid < total; tid += stride) {
        int e = (int)(tid >> 4);
        int q = (int)(tid & 15);
        int r = rows[e];
        int c = cols[e];
        float v = vals[e];
        float4 xv = reinterpret_cast<const float4*>(x)[(size_t)c * 16 + q];
        float* yp = y + (size_t)r * LATENT + q * 4;
        atomicAdd(yp + 0, v * xv.x);
        atomicAdd(yp + 1, v * xv.y);
        atomicAdd(yp + 2, v * xv.z);
        atomicAdd(yp + 3, v * xv.w);
    }
}

__global__ void finalize_kernel(const float* __restrict__ alpha, const float* __restrict__ x,
                                float* __restrict__ out, int N) {
    long long tid = (long long)blockIdx.x * blockDim.x + threadIdx.x;
    long long total = (long long)N * 16;
    long long stride = (long long)gridDim.x * blockDim.x;
    for (; tid < total; tid += stride) {
        int i = (int)(tid >> 4);
        float a = 1.0f / (1.0f + __expf(-alpha[i]));
        float4 o = reinterpret_cast<float4*>(out)[tid];
        float4 xv = reinterpret_cast<const float4*>(x)[tid];
        o.x = a * o.x - xv.x;
        o.y = a * o.y - xv.y;
        o.z = a * o.z - xv.z;
        o.w = a * o.w - xv.w;
        reinterpret_cast<float4*>(out)[tid] = o;
    }
}

// ---------------------------------------------------------------------------

extern "C" void kernel_launch(void* const* d_in, const int* in_sizes, int n_in,
                              void* d_out, int out_size, void* d_ws, size_t ws_size,
                              hipStream_t stream) {
    // setup_inputs order: t, x, alpha_train, edge_rows, edge_cols, edge_vals
    const float* x     = (const float*)d_in[1];
    const float* alpha = (const float*)d_in[2];
    const int*   rows  = (const int*)d_in[3];
    const int*   cols  = (const int*)d_in[4];
    const float* vals  = (const float*)d_in[5];

    const int N = in_sizes[2];   // 100000
    const int E = in_sizes[3];   // 3200000
    float* out = (float*)d_out;

    const int block = 256;
    const int nsub   = (N + SUB_ROWS - 1) >> SUB_SHIFT;   // 782
    const int ntiles = (E + TILE - 1) / TILE;             // 391
    const int nblk_N = (N + 255) / 256;

    auto align256 = [](size_t v) { return (v + 255) & ~(size_t)255; };

    // --- Fast path layout. part[] aliases spair (dead before spair written);
    //     ax1 aliases tmp (dead after subsort).
    size_t tmp_bytes = ((size_t)E + 8 * (size_t)nsub) * sizeof(int2);
    size_t ax1_bytes = (size_t)N * LATENT * sizeof(float);
    size_t RA = tmp_bytes > ax1_bytes ? tmp_bytes : ax1_bytes;
    size_t o_tmp    = 0;
    size_t o_spair  = align256(o_tmp + RA);
    size_t o_off    = align256(o_spair + (size_t)E * sizeof(int2));
    size_t o_cnt    = align256(o_off + (size_t)N * sizeof(int));
    size_t o_csr0   = align256(o_cnt + (size_t)N * sizeof(int));
    size_t o_tstart = align256(o_csr0 + (size_t)nsub * sizeof(int));
    size_t o_stot   = align256(o_tstart + (size_t)nsub * sizeof(int));
    size_t o_gcur   = align256(o_stot + (size_t)nsub * sizeof(int));
    size_t needed   = o_gcur + (size_t)nsub * sizeof(int);
    size_t part_bytes = (size_t)HIST_BLOCKS * nsub * sizeof(int);

    if (ws_size >= needed && nsub <= NSUB_PAD && N <= (1 << COLBITS) &&
        part_bytes <= (size_t)E * sizeof(int2)) {
        char* ws = (char*)d_ws;
        int2*  tmp    = (int2*)(ws + o_tmp);
        float* ax1    = (float*)(ws + o_tmp);      // aliases tmp
        int2*  spair  = (int2*)(ws + o_spair);
        int*   part   = (int*)(ws + o_spair);      // aliases spair (earlier lifetime)
        int*   off    = (int*)(ws + o_off);
        int*   cnt    = (int*)(ws + o_cnt);
        int*   csr0   = (int*)(ws + o_csr0);
        int*   tstart = (int*)(ws + o_tstart);
        int*   stot   = (int*)(ws + o_stot);
        int*   gcur   = (int*)(ws + o_gcur);

        subhist_kernel<<<HIST_BLOCKS, 256, 0, stream>>>(rows, part, E, nsub);
        subscan_kernel<<<1, 256, 0, stream>>>(part, csr0, tstart, stot, gcur, nsub,
                                              HIST_BLOCKS);
        binscatter_kernel<<<ntiles, 256, 0, stream>>>(rows, cols, vals, gcur, tmp, E, nsub);
        subsort_kernel<<<nsub, 256, 0, stream>>>(tmp, tstart, stot, csr0, off, cnt, spair, N);

        int rows_per_block = block / 64;
        int grid_rows = (N + rows_per_block - 1) / rows_per_block;
        spmm_gather_kernel<<<grid_rows, block, 0, stream>>>(off, cnt, spair, x, ax1, N);
        spmm_gather_fused_kernel<<<grid_rows, block, 0, stream>>>(off, cnt, spair, ax1,
                                                                  alpha, x, out, N);
        return;
    }

    // --- Fallback A: round-2 direct scatter path
    size_t f_ax1   = 0;
    size_t f_spair = align256(f_ax1 + (size_t)N * LATENT * sizeof(float));
    size_t f_cnt   = align256(f_spair + (size_t)E * sizeof(int2));
    size_t f_off   = align256(f_cnt + (size_t)N * sizeof(int));
    size_t f_cur   = align256(f_off + (size_t)N * sizeof(int));
    size_t f_bsum  = align256(f_cur + (size_t)N * sizeof(int));
    size_t f_need  = f_bsum + 512 * sizeof(int);
    const int grid_E = (E + block - 1) / block;

    if (ws_size >= f_need && nblk_N <= 512) {
        char* ws = (char*)d_ws;
        float* ax1   = (float*)(ws + f_ax1);
        int2*  spair = (int2*)(ws + f_spair);
        int*   cnt   = (int*)(ws + f_cnt);
        int*   off   = (int*)(ws + f_off);
        int*   cur   = (int*)(ws + f_cur);
        int*   bsum  = (int*)(ws + f_bsum);

        hipMemsetAsync(cnt, 0, (size_t)N * sizeof(int), stream);
        histogram_kernel<<<grid_E, block, 0, stream>>>(rows, cnt, E);
        block_sum_kernel<<<nblk_N, 256, 0, stream>>>(cnt, bsum, N);
        scan_partials_kernel<<<1, 512, 0, stream>>>(bsum, nblk_N);
        chunk_scan_kernel<<<nblk_N, 256, 0, stream>>>(cnt, bsum, off, N);
        init_cursor_kernel<<<nblk_N, 256, 0, stream>>>(off, cur, N);
        scatter_kernel<<<grid_E, block, 0, stream>>>(rows, cols, vals, cur, spair, E);

        int rows_per_block = block / 64;
        int grid_rows = (N + rows_per_block - 1) / rows_per_block;
        spmm_gather_kernel<<<grid_rows, block, 0, stream>>>(off, cnt, spair, x, ax1, N);
        spmm_gather_fused_kernel<<<grid_rows, block, 0, stream>>>(off, cnt, spair, ax1,
                                                                  alpha, x, out, N);
        return;
    }

    // --- Fallback B: atomic scatter path
    {
        float* ax1 = (float*)d_ws;
        const size_t feat_bytes = (size_t)N * LATENT * sizeof(float);
        hipMemsetAsync(ax1, 0, feat_bytes, stream);
        hipMemsetAsync(out, 0, feat_bytes, stream);
        long long work = (long long)E * 16;
        int grid_spmm = (int)((work + block - 1) / block);
        spmm_atomic_kernel<<<grid_spmm, block, 0, stream>>>(rows, cols, vals, x, ax1, E);
        spmm_atomic_kernel<<<grid_spmm, block, 0, stream>>>(rows, cols, vals, ax1, out, E);
        long long fwork = (long long)N * 16;
        int grid_fin = (int)((fwork + block - 1) / block);
        finalize_kernel<<<grid_fin, block, 0, stream>>>(alpha, x, out, N);
    }
}

// Round 6
// 339.015 us; speedup vs baseline: 1.9572x; 1.6101x over previous
//
#include <hip/hip_runtime.h>

#define LATENT 64
#define SUB_SHIFT 7
#define SUB_ROWS 128
#define COLBITS 17
#define COL_MASK ((1 << COLBITS) - 1)
#define HIST_BLOCKS 256
#define TILE 8192
#define NSUB_PAD 1024

// ---------------------------------------------------------------------------
// Kernel A: per-block sub-bucket histogram partials (no global atomics)
// ---------------------------------------------------------------------------
__global__ void subhist_kernel(const int* __restrict__ rows, int* __restrict__ part,
                               int E, int nsub) {
    __shared__ int h[NSUB_PAD];
    int t = threadIdx.x;
    for (int i = t; i < NSUB_PAD; i += blockDim.x) h[i] = 0;
    __syncthreads();
    for (int e = blockIdx.x * blockDim.x + t; e < E; e += gridDim.x * blockDim.x)
        atomicAdd(&h[rows[e] >> SUB_SHIFT], 1);
    __syncthreads();
    for (int i = t; i < nsub; i += blockDim.x) part[blockIdx.x * nsub + i] = h[i];
}

// ---------------------------------------------------------------------------
// Kernel A2: parallel reduction of partials -> tot[s]. One block per sub-bucket.
// ---------------------------------------------------------------------------
__global__ void reduce_partials_kernel(const int* __restrict__ part, int* __restrict__ tot,
                                       int nsub, int nblk) {
    __shared__ int s[256];
    int sidx = blockIdx.x;
    int t = threadIdx.x;
    int acc = 0;
    for (int b = t; b < nblk; b += 256) acc += part[b * nsub + sidx];
    s[t] = acc;
    __syncthreads();
    for (int o = 128; o > 0; o >>= 1) {
        if (t < o) s[t] += s[t + o];
        __syncthreads();
    }
    if (t == 0) tot[sidx] = s[0];
}

// ---------------------------------------------------------------------------
// Kernel B (1 block): exclusive scan of tot -> csr0, tstart, stot, gcur
// tstart[s] = csr0[s] + 8*s  (8-payload gap => adjacent bins never share a line)
// ---------------------------------------------------------------------------
__global__ void subscan_kernel(const int* __restrict__ tot_in, int* __restrict__ csr0,
                               int* __restrict__ tstart, int* __restrict__ stot,
                               int* __restrict__ gcur, int nsub) {
    __shared__ int tot[NSUB_PAD];
    __shared__ int sc[256];
    int t = threadIdx.x;
    for (int i = t; i < NSUB_PAD; i += 256) tot[i] = (i < nsub) ? tot_in[i] : 0;
    __syncthreads();
    int c0 = tot[4 * t], c1 = tot[4 * t + 1], c2 = tot[4 * t + 2], c3 = tot[4 * t + 3];
    int csum = c0 + c1 + c2 + c3;
    sc[t] = csum;
    __syncthreads();
    for (int o = 1; o < 256; o <<= 1) {
        int u = (t >= o) ? sc[t - o] : 0;
        __syncthreads();
        sc[t] += u;
        __syncthreads();
    }
    int pre = sc[t] - csum;   // exclusive chunk base
    int s0 = 4 * t;
    if (s0 < nsub)     { csr0[s0] = pre;     stot[s0] = c0;     int ts = pre + 8 * s0;       tstart[s0] = ts;     gcur[s0] = ts; }
    pre += c0;
    if (s0 + 1 < nsub) { csr0[s0 + 1] = pre; stot[s0 + 1] = c1; int ts = pre + 8 * (s0 + 1); tstart[s0 + 1] = ts; gcur[s0 + 1] = ts; }
    pre += c1;
    if (s0 + 2 < nsub) { csr0[s0 + 2] = pre; stot[s0 + 2] = c2; int ts = pre + 8 * (s0 + 2); tstart[s0 + 2] = ts; gcur[s0 + 2] = ts; }
    pre += c2;
    if (s0 + 3 < nsub) { csr0[s0 + 3] = pre; stot[s0 + 3] = c3; int ts = pre + 8 * (s0 + 3); tstart[s0 + 3] = ts; gcur[s0 + 3] = ts; }
}

// ---------------------------------------------------------------------------
// Pass 1: tile-local LDS bucket sort, then append contiguous runs to bins.
// Each run is written by consecutive threads of ONE block -> single-CU lines.
// ---------------------------------------------------------------------------
__global__ void __launch_bounds__(256, 2) binscatter_kernel(
        const int* __restrict__ rows, const int* __restrict__ cols,
        const float* __restrict__ vals, int* __restrict__ gcur,
        int2* __restrict__ tmp, int E, int nsub) {
    __shared__ int hist[NSUB_PAD];    // histogram, then cursor
    __shared__ int base[NSUB_PAD];    // exclusive scan
    __shared__ int gbase[NSUB_PAD];   // global run start - local base
    __shared__ int2 stage[TILE];
    __shared__ int sc[256];
    int t = threadIdx.x;
    int tb = blockIdx.x * TILE;
    int tilecnt = E - tb; if (tilecnt > TILE) tilecnt = TILE;

    for (int i = t; i < NSUB_PAD; i += 256) hist[i] = 0;
    __syncthreads();
    #pragma unroll
    for (int k = 0; k < TILE / 256; ++k) {
        int e = tb + k * 256 + t;
        if (e < E) atomicAdd(&hist[rows[e] >> SUB_SHIFT], 1);
    }
    __syncthreads();
    // exclusive scan hist -> base over NSUB_PAD (chunk of 4 per thread)
    int c0 = hist[4 * t], c1 = hist[4 * t + 1], c2 = hist[4 * t + 2], c3 = hist[4 * t + 3];
    int csum = c0 + c1 + c2 + c3;
    sc[t] = csum;
    __syncthreads();
    for (int o = 1; o < 256; o <<= 1) {
        int u = (t >= o) ? sc[t - o] : 0;
        __syncthreads();
        sc[t] += u;
        __syncthreads();
    }
    int ex = sc[t] - csum;
    base[4 * t] = ex;
    base[4 * t + 1] = ex + c0;
    base[4 * t + 2] = ex + c0 + c1;
    base[4 * t + 3] = ex + c0 + c1 + c2;
    __syncthreads();
    for (int i = t; i < NSUB_PAD; i += 256) hist[i] = 0;   // reset as cursors
    __syncthreads();
    // place payloads into stage, sorted by bucket
    #pragma unroll
    for (int k = 0; k < TILE / 256; ++k) {
        int e = tb + k * 256 + t;
        if (e < E) {
            int r = rows[e];
            int b = r >> SUB_SHIFT;
            int pos = base[b] + atomicAdd(&hist[b], 1);
            stage[pos] = make_int2(cols[e] | ((r & (SUB_ROWS - 1)) << COLBITS),
                                   __float_as_int(vals[e]));
        }
    }
    __syncthreads();
    // reserve global space (one atomic per non-empty bucket per tile)
    for (int i = t; i < nsub; i += 256) {
        int n = hist[i];
        int gb = 0;
        if (n > 0) gb = atomicAdd(&gcur[i], n);
        gbase[i] = gb - base[i];
    }
    __syncthreads();
    // copy out: consecutive p -> consecutive dst within each run (coalesced)
    for (int p = t; p < tilecnt; p += 256) {
        int lo = 0, hi = nsub;
        while (hi - lo > 1) { int mid = (lo + hi) >> 1; if (base[mid] <= p) lo = mid; else hi = mid; }
        tmp[gbase[lo] + p] = stage[p];
    }
}

// ---------------------------------------------------------------------------
// Pass 2: one block per sub-bucket -> per-row counts, off/cnt, sorted spair.
// All writes land in the block's private ~32KB CSR window (single XCD).
// ---------------------------------------------------------------------------
__global__ void subsort_kernel(const int2* __restrict__ tmp, const int* __restrict__ tstart,
                               const int* __restrict__ stot, const int* __restrict__ csr0,
                               int* __restrict__ off, int* __restrict__ cnt,
                               int2* __restrict__ spair, int N) {
    __shared__ int lcnt[SUB_ROWS], lpos[SUB_ROWS], lcur[SUB_ROWS];
    int s = blockIdx.x;
    int t = threadIdx.x;
    int beg = tstart[s], n = stot[s], c0 = csr0[s];
    if (t < SUB_ROWS) lcnt[t] = 0;
    __syncthreads();
    for (int i = t; i < n; i += blockDim.x)
        atomicAdd(&lcnt[(tmp[beg + i].x >> COLBITS) & (SUB_ROWS - 1)], 1);
    __syncthreads();
    if (t < SUB_ROWS) lpos[t] = lcnt[t];
    __syncthreads();
    for (int o = 1; o < SUB_ROWS; o <<= 1) {
        int u = (t < SUB_ROWS && t >= o) ? lpos[t - o] : 0;
        __syncthreads();
        if (t < SUB_ROWS) lpos[t] += u;
        __syncthreads();
    }
    if (t < SUB_ROWS) {
        int excl = lpos[t] - lcnt[t];
        lcur[t] = excl;
        int row = (s << SUB_SHIFT) + t;
        if (row < N) { off[row] = c0 + excl; cnt[row] = lcnt[t]; }
    }
    __syncthreads();
    for (int i = t; i < n; i += blockDim.x) {
        int2 w = tmp[beg + i];
        int rl = (w.x >> COLBITS) & (SUB_ROWS - 1);
        int p = atomicAdd(&lcur[rl], 1);
        spair[c0 + p] = make_int2(w.x & COL_MASK, w.y);
    }
}

// ---------------------------------------------------------------------------
// Gather SpMM: one 64-lane wave per output row; lane = feature index.
// ---------------------------------------------------------------------------
__global__ void spmm_gather_kernel(const int* __restrict__ off, const int* __restrict__ cnt,
                                   const int2* __restrict__ spair,
                                   const float* __restrict__ x, float* __restrict__ y, int N) {
    int wid = blockIdx.x * (blockDim.x >> 6) + (threadIdx.x >> 6);
    int lane = threadIdx.x & 63;
    if (wid >= N) return;
    int e = off[wid];
    int end = e + cnt[wid];
    float acc = 0.f;
    for (; e + 8 <= end; e += 8) {
        int2 p0 = spair[e], p1 = spair[e + 1], p2 = spair[e + 2], p3 = spair[e + 3];
        int2 p4 = spair[e + 4], p5 = spair[e + 5], p6 = spair[e + 6], p7 = spair[e + 7];
        acc += __int_as_float(p0.y) * x[(size_t)p0.x * LATENT + lane];
        acc += __int_as_float(p1.y) * x[(size_t)p1.x * LATENT + lane];
        acc += __int_as_float(p2.y) * x[(size_t)p2.x * LATENT + lane];
        acc += __int_as_float(p3.y) * x[(size_t)p3.x * LATENT + lane];
        acc += __int_as_float(p4.y) * x[(size_t)p4.x * LATENT + lane];
        acc += __int_as_float(p5.y) * x[(size_t)p5.x * LATENT + lane];
        acc += __int_as_float(p6.y) * x[(size_t)p6.x * LATENT + lane];
        acc += __int_as_float(p7.y) * x[(size_t)p7.x * LATENT + lane];
    }
    for (; e < end; ++e) {
        int2 p = spair[e];
        acc += __int_as_float(p.y) * x[(size_t)p.x * LATENT + lane];
    }
    y[(size_t)wid * LATENT + lane] = acc;
}

__global__ void spmm_gather_fused_kernel(const int* __restrict__ off, const int* __restrict__ cnt,
                                         const int2* __restrict__ spair,
                                         const float* __restrict__ ax1,
                                         const float* __restrict__ alpha,
                                         const float* __restrict__ x,
                                         float* __restrict__ out, int N) {
    int wid = blockIdx.x * (blockDim.x >> 6) + (threadIdx.x >> 6);
    int lane = threadIdx.x & 63;
    if (wid >= N) return;
    int e = off[wid];
    int end = e + cnt[wid];
    float acc = 0.f;
    for (; e + 8 <= end; e += 8) {
        int2 p0 = spair[e], p1 = spair[e + 1], p2 = spair[e + 2], p3 = spair[e + 3];
        int2 p4 = spair[e + 4], p5 = spair[e + 5], p6 = spair[e + 6], p7 = spair[e + 7];
        acc += __int_as_float(p0.y) * ax1[(size_t)p0.x * LATENT + lane];
        acc += __int_as_float(p1.y) * ax1[(size_t)p1.x * LATENT + lane];
        acc += __int_as_float(p2.y) * ax1[(size_t)p2.x * LATENT + lane];
        acc += __int_as_float(p3.y) * ax1[(size_t)p3.x * LATENT + lane];
        acc += __int_as_float(p4.y) * ax1[(size_t)p4.x * LATENT + lane];
        acc += __int_as_float(p5.y) * ax1[(size_t)p5.x * LATENT + lane];
        acc += __int_as_float(p6.y) * ax1[(size_t)p6.x * LATENT + lane];
        acc += __int_as_float(p7.y) * ax1[(size_t)p7.x * LATENT + lane];
    }
    for (; e < end; ++e) {
        int2 p = spair[e];
        acc += __int_as_float(p.y) * ax1[(size_t)p.x * LATENT + lane];
    }
    float a = 1.0f / (1.0f + __expf(-alpha[wid]));
    out[(size_t)wid * LATENT + lane] = a * acc - x[(size_t)wid * LATENT + lane];
}

// ---------------------------------------------------------------------------
// Fallback kernels (round-2 direct-scatter path + atomic path)
// ---------------------------------------------------------------------------
__global__ void histogram_kernel(const int* __restrict__ rows, int* __restrict__ cnt, int E) {
    int e = blockIdx.x * blockDim.x + threadIdx.x;
    if (e < E) atomicAdd(&cnt[rows[e]], 1);
}

__global__ void block_sum_kernel(const int* __restrict__ cnt, int* __restrict__ bsum, int N) {
    __shared__ int s[256];
    int t = threadIdx.x;
    int i = blockIdx.x * 256 + t;
    s[t] = (i < N) ? cnt[i] : 0;
    __syncthreads();
    for (int o = 128; o > 0; o >>= 1) {
        if (t < o) s[t] += s[t + o];
        __syncthreads();
    }
    if (t == 0) bsum[blockIdx.x] = s[0];
}

__global__ void scan_partials_kernel(int* __restrict__ bsum, int nblk) {
    __shared__ int s[512];
    int t = threadIdx.x;
    int v = (t < nblk) ? bsum[t] : 0;
    s[t] = v;
    __syncthreads();
    for (int o = 1; o < 512; o <<= 1) {
        int u = (t >= o) ? s[t - o] : 0;
        __syncthreads();
        s[t] += u;
        __syncthreads();
    }
    if (t < nblk) bsum[t] = s[t] - v;
}

__global__ void chunk_scan_kernel(const int* __restrict__ cnt, const int* __restrict__ bsum,
                                  int* __restrict__ off, int N) {
    __shared__ int s[256];
    int t = threadIdx.x;
    int i = blockIdx.x * 256 + t;
    int v = (i < N) ? cnt[i] : 0;
    s[t] = v;
    __syncthreads();
    for (int o = 1; o < 256; o <<= 1) {
        int u = (t >= o) ? s[t - o] : 0;
        __syncthreads();
        s[t] += u;
        __syncthreads();
    }
    if (i < N) off[i] = s[t] - v + bsum[blockIdx.x];
}

__global__ void init_cursor_kernel(const int* __restrict__ off, int* __restrict__ cur, int N) {
    int i = blockIdx.x * blockDim.x + threadIdx.x;
    if (i < N) cur[i] = off[i];
}

__global__ void scatter_kernel(const int* __restrict__ rows, const int* __restrict__ cols,
                               const float* __restrict__ vals, int* __restrict__ cursor,
                               int2* __restrict__ spair, int E) {
    int e = blockIdx.x * blockDim.x + threadIdx.x;
    if (e < E) {
        int r = rows[e];
        int p = atomicAdd(&cursor[r], 1);
        spair[p] = make_int2(cols[e], __float_as_int(vals[e]));
    }
}

__global__ void spmm_atomic_kernel(const int* __restrict__ rows, const int* __restrict__ cols,
                                   const float* __restrict__ vals, const float* __restrict__ x,
                                   float* __restrict__ y, int E) {
    long long tid = (long long)blockIdx.x * blockDim.x + threadIdx.x;
    long long total = (long long)E * 16;
    long long stride = (long long)gridDim.x * blockDim.x;
    for (; tid < total; tid += stride) {
        int e = (int)(tid >> 4);
        int q = (int)(tid & 15);
        int r = rows[e];
        int c = cols[e];
        float v = vals[e];
        float4 xv = reinterpret_cast<const float4*>(x)[(size_t)c * 16 + q];
        float* yp = y + (size_t)r * LATENT + q * 4;
        atomicAdd(yp + 0, v * xv.x);
        atomicAdd(yp + 1, v * xv.y);
        atomicAdd(yp + 2, v * xv.z);
        atomicAdd(yp + 3, v * xv.w);
    }
}

__global__ void finalize_kernel(const float* __restrict__ alpha, const float* __restrict__ x,
                                float* __restrict__ out, int N) {
    long long tid = (long long)blockIdx.x * blockDim.x + threadIdx.x;
    long long total = (long long)N * 16;
    long long stride = (long long)gridDim.x * blockDim.x;
    for (; tid < total; tid += stride) {
        int i = (int)(tid >> 4);
        float a = 1.0f / (1.0f + __expf(-alpha[i]));
        float4 o = reinterpret_cast<float4*>(out)[tid];
        float4 xv = reinterpret_cast<const float4*>(x)[tid];
        o.x = a * o.x - xv.x;
        o.y = a * o.y - xv.y;
        o.z = a * o.z - xv.z;
        o.w = a * o.w - xv.w;
        reinterpret_cast<float4*>(out)[tid] = o;
    }
}

// ---------------------------------------------------------------------------

extern "C" void kernel_launch(void* const* d_in, const int* in_sizes, int n_in,
                              void* d_out, int out_size, void* d_ws, size_t ws_size,
                              hipStream_t stream) {
    // setup_inputs order: t, x, alpha_train, edge_rows, edge_cols, edge_vals
    const float* x     = (const float*)d_in[1];
    const float* alpha = (const float*)d_in[2];
    const int*   rows  = (const int*)d_in[3];
    const int*   cols  = (const int*)d_in[4];
    const float* vals  = (const float*)d_in[5];

    const int N = in_sizes[2];   // 100000
    const int E = in_sizes[3];   // 3200000
    float* out = (float*)d_out;

    const int block = 256;
    const int nsub   = (N + SUB_ROWS - 1) >> SUB_SHIFT;   // 782
    const int ntiles = (E + TILE - 1) / TILE;             // 391
    const int nblk_N = (N + 255) / 256;

    auto align256 = [](size_t v) { return (v + 255) & ~(size_t)255; };

    // --- Fast path layout. part[] aliases spair (dead before spair written);
    //     ax1 aliases tmp (dead after subsort).
    size_t tmp_bytes = ((size_t)E + 8 * (size_t)nsub) * sizeof(int2);
    size_t ax1_bytes = (size_t)N * LATENT * sizeof(float);
    size_t RA = tmp_bytes > ax1_bytes ? tmp_bytes : ax1_bytes;
    size_t o_tmp    = 0;
    size_t o_spair  = align256(o_tmp + RA);
    size_t o_off    = align256(o_spair + (size_t)E * sizeof(int2));
    size_t o_cnt    = align256(o_off + (size_t)N * sizeof(int));
    size_t o_csr0   = align256(o_cnt + (size_t)N * sizeof(int));
    size_t o_tstart = align256(o_csr0 + (size_t)nsub * sizeof(int));
    size_t o_stot   = align256(o_tstart + (size_t)nsub * sizeof(int));
    size_t o_gcur   = align256(o_stot + (size_t)nsub * sizeof(int));
    size_t o_tot    = align256(o_gcur + (size_t)nsub * sizeof(int));
    size_t needed   = o_tot + (size_t)nsub * sizeof(int);
    size_t part_bytes = (size_t)HIST_BLOCKS * nsub * sizeof(int);

    if (ws_size >= needed && nsub <= NSUB_PAD && N <= (1 << COLBITS) &&
        part_bytes <= (size_t)E * sizeof(int2)) {
        char* ws = (char*)d_ws;
        int2*  tmp    = (int2*)(ws + o_tmp);
        float* ax1    = (float*)(ws + o_tmp);      // aliases tmp
        int2*  spair  = (int2*)(ws + o_spair);
        int*   part   = (int*)(ws + o_spair);      // aliases spair (earlier lifetime)
        int*   off    = (int*)(ws + o_off);
        int*   cnt    = (int*)(ws + o_cnt);
        int*   csr0   = (int*)(ws + o_csr0);
        int*   tstart = (int*)(ws + o_tstart);
        int*   stot   = (int*)(ws + o_stot);
        int*   gcur   = (int*)(ws + o_gcur);
        int*   tot    = (int*)(ws + o_tot);

        subhist_kernel<<<HIST_BLOCKS, 256, 0, stream>>>(rows, part, E, nsub);
        reduce_partials_kernel<<<nsub, 256, 0, stream>>>(part, tot, nsub, HIST_BLOCKS);
        subscan_kernel<<<1, 256, 0, stream>>>(tot, csr0, tstart, stot, gcur, nsub);
        binscatter_kernel<<<ntiles, 256, 0, stream>>>(rows, cols, vals, gcur, tmp, E, nsub);
        subsort_kernel<<<nsub, 256, 0, stream>>>(tmp, tstart, stot, csr0, off, cnt, spair, N);

        int rows_per_block = block / 64;
        int grid_rows = (N + rows_per_block - 1) / rows_per_block;
        spmm_gather_kernel<<<grid_rows, block, 0, stream>>>(off, cnt, spair, x, ax1, N);
        spmm_gather_fused_kernel<<<grid_rows, block, 0, stream>>>(off, cnt, spair, ax1,
                                                                  alpha, x, out, N);
        return;
    }

    // --- Fallback A: round-2 direct scatter path
    size_t f_ax1   = 0;
    size_t f_spair = align256(f_ax1 + (size_t)N * LATENT * sizeof(float));
    size_t f_cnt   = align256(f_spair + (size_t)E * sizeof(int2));
    size_t f_off   = align256(f_cnt + (size_t)N * sizeof(int));
    size_t f_cur   = align256(f_off + (size_t)N * sizeof(int));
    size_t f_bsum  = align256(f_cur + (size_t)N * sizeof(int));
    size_t f_need  = f_bsum + 512 * sizeof(int);
    const int grid_E = (E + block - 1) / block;

    if (ws_size >= f_need && nblk_N <= 512) {
        char* ws = (char*)d_ws;
        float* ax1   = (float*)(ws + f_ax1);
        int2*  spair = (int2*)(ws + f_spair);
        int*   cnt   = (int*)(ws + f_cnt);
        int*   off   = (int*)(ws + f_off);
        int*   cur   = (int*)(ws + f_cur);
        int*   bsum  = (int*)(ws + f_bsum);

        hipMemsetAsync(cnt, 0, (size_t)N * sizeof(int), stream);
        histogram_kernel<<<grid_E, block, 0, stream>>>(rows, cnt, E);
        block_sum_kernel<<<nblk_N, 256, 0, stream>>>(cnt, bsum, N);
        scan_partials_kernel<<<1, 512, 0, stream>>>(bsum, nblk_N);
        chunk_scan_kernel<<<nblk_N, 256, 0, stream>>>(cnt, bsum, off, N);
        init_cursor_kernel<<<nblk_N, 256, 0, stream>>>(off, cur, N);
        scatter_kernel<<<grid_E, block, 0, stream>>>(rows, cols, vals, cur, spair, E);

        int rows_per_block = block / 64;
        int grid_rows = (N + rows_per_block - 1) / rows_per_block;
        spmm_gather_kernel<<<grid_rows, block, 0, stream>>>(off, cnt, spair, x, ax1, N);
        spmm_gather_fused_kernel<<<grid_rows, block, 0, stream>>>(off, cnt, spair, ax1,
                                                                  alpha, x, out, N);
        return;
    }

    // --- Fallback B: atomic scatter path
    {
        float* ax1 = (float*)d_ws;
        const size_t feat_bytes = (size_t)N * LATENT * sizeof(float);
        hipMemsetAsync(ax1, 0, feat_bytes, stream);
        hipMemsetAsync(out, 0, feat_bytes, stream);
        long long work = (long long)E * 16;
        int grid_spmm = (int)((work + block - 1) / block);
        spmm_atomic_kernel<<<grid_spmm, block, 0, stream>>>(rows, cols, vals, x, ax1, E);
        spmm_atomic_kernel<<<grid_spmm, block, 0, stream>>>(rows, cols, vals, ax1, out, E);
        long long fwork = (long long)N * 16;
        int grid_fin = (int)((fwork + block - 1) / block);
        finalize_kernel<<<grid_fin, block, 0, stream>>>(alpha, x, out, N);
    }
}